// Round 1
// baseline (75.136 us; speedup 1.0000x reference)
//
#include <hip/hip_runtime.h>
#include <stdint.h>

typedef unsigned short u16;
typedef unsigned int u32;
typedef __bf16 bf16x8 __attribute__((ext_vector_type(8)));
typedef float f32x4 __attribute__((ext_vector_type(4)));

// ---------------- helpers ----------------

__device__ __forceinline__ u16 f2bf(float f) {
    u32 u = __builtin_bit_cast(u32, f);
    u32 r = (u + 0x7FFFu + ((u >> 16) & 1u)) >> 16;
    return (u16)r;
}

__device__ __forceinline__ void gload_lds16(const u16* g, u16* l) {
    __builtin_amdgcn_global_load_lds(
        (const __attribute__((address_space(1))) void*)g,
        (__attribute__((address_space(3))) void*)l,
        16, 0, 0);
}

// ---------------- kernel 1: x fp32 -> bf16 ----------------

__global__ __launch_bounds__(256) void conv_x_kernel(const float* __restrict__ x,
                                                     u16* __restrict__ xb, int nElem) {
    int i = (blockIdx.x * 256 + threadIdx.x) * 8;
    if (i + 8 > nElem) return;
    float4 a = *reinterpret_cast<const float4*>(x + i);
    float4 b = *reinterpret_cast<const float4*>(x + i + 4);
    uint4 pk;
    pk.x = (u32)f2bf(a.x) | ((u32)f2bf(a.y) << 16);
    pk.y = (u32)f2bf(a.z) | ((u32)f2bf(a.w) << 16);
    pk.z = (u32)f2bf(b.x) | ((u32)f2bf(b.y) << 16);
    pk.w = (u32)f2bf(b.z) | ((u32)f2bf(b.w) << 16);
    *reinterpret_cast<uint4*>(xb + i) = pk;
}

// ---------------- kernel 2: fused weight precompute ----------------
// Wt[o*4+s][i] (bf16, [4096][1024] row-major) =
//   sum_{q,r} c0[b,w,q,s] * c1[q,c,x,r,s] * c2[r,d,y,s]
// where i=(b*128+c*8+d), o=(w*128+x*8+y).
// grid: 128 blocks = (b*16 + c); 256 threads.

__global__ __launch_bounds__(256) void prep_w_kernel(const float* __restrict__ c0,
                                                     const float* __restrict__ c1,
                                                     const float* __restrict__ c2,
                                                     u16* __restrict__ Wt) {
    __shared__ float l_c0[256];   // [w][q][s]           (slice at fixed b)
    __shared__ float l_c1[4096];  // [q][x][r][s]        (slice at fixed c)
    __shared__ float l_c2[2048];  // [r][d][y][s]        (full)
    __shared__ float l_w1[4096];  // [w][x][r][s]

    const int t = threadIdx.x;
    const int bc = blockIdx.x;
    const int b = bc >> 4, c = bc & 15;

    // core0 flat: ((b*8+w)*8+q)*4+s ; slice for b = 256 consecutive floats
    l_c0[t] = c0[b * 256 + t];
    // core1 flat: (((q*16+c)*16+x)*8+r)*4+s ; per q: 512 consecutive floats
#pragma unroll
    for (int q = 0; q < 8; ++q) {
        l_c1[q * 512 + t]       = c1[(q * 16 + c) * 512 + t];
        l_c1[q * 512 + t + 256] = c1[(q * 16 + c) * 512 + t + 256];
    }
#pragma unroll
    for (int j = 0; j < 8; ++j) l_c2[t + 256 * j] = c2[t + 256 * j];
    __syncthreads();

    // W1[w][x][r][s] = sum_q c0[w,q,s] * c1[q,x,r,s]
#pragma unroll
    for (int j = 0; j < 16; ++j) {
        int idx = t + 256 * j;        // ((w*16+x)*8+r)*4+s
        int s = idx & 3;
        int r = (idx >> 2) & 7;
        int x = (idx >> 5) & 15;
        int w = idx >> 9;
        float acc = 0.f;
#pragma unroll
        for (int q = 0; q < 8; ++q)
            acc += l_c0[(w * 8 + q) * 4 + s] * l_c1[q * 512 + (x * 8 + r) * 4 + s];
        l_w1[idx] = acc;
    }
    __syncthreads();

    // Wt[idx=(o*4+s)][b*128+c*8+d] = sum_r W1[w,x,r,s] * c2[r,d,y,s]
#pragma unroll
    for (int j = 0; j < 16; ++j) {
        int idx = t + 256 * j;        // ((w*16+x)*8+y)*4+s == o*4+s
        int s = idx & 3;
        int y = (idx >> 2) & 7;
        int x = (idx >> 5) & 15;
        int w = idx >> 9;
        float acc[8] = {0.f, 0.f, 0.f, 0.f, 0.f, 0.f, 0.f, 0.f};
#pragma unroll
        for (int r = 0; r < 8; ++r) {
            float w1 = l_w1[((w * 16 + x) * 8 + r) * 4 + s];
#pragma unroll
            for (int d = 0; d < 8; ++d)
                acc[d] += w1 * l_c2[((r * 8 + d) * 8 + y) * 4 + s];
        }
        uint4 pk;
        pk.x = (u32)f2bf(acc[0]) | ((u32)f2bf(acc[1]) << 16);
        pk.y = (u32)f2bf(acc[2]) | ((u32)f2bf(acc[3]) << 16);
        pk.z = (u32)f2bf(acc[4]) | ((u32)f2bf(acc[5]) << 16);
        pk.w = (u32)f2bf(acc[6]) | ((u32)f2bf(acc[7]) << 16);
        *reinterpret_cast<uint4*>(&Wt[(size_t)idx * 1024 + b * 128 + c * 8]) = pk;
    }
}

// ---------------- kernel 3: GEMM  C[M][N] = A[M][K] * B[N][K]^T ----------------
// A = x_bf16 [M=4096][K=1024], B = Wt [N=4096][K=1024], C fp32 [M][N].
// m97 structure: 128x128 tile, BK=64, 4 waves (2x2), 4x4 frags of 16x16x32 bf16.

#define BM 128
#define BN 128
#define BK 64

__global__ __launch_bounds__(256) void gemm_bt_kernel(const u16* __restrict__ A,
                                                      const u16* __restrict__ B,
                                                      float* __restrict__ C,
                                                      int M, int N, int K) {
    __shared__ u16 As[BM * BK];  // [row][k] row-major, 16 KB
    __shared__ u16 Bs[BN * BK];  // [col][k] row-major, 16 KB

    const int t  = threadIdx.x;
    const int wv = t >> 6;        // wave 0..3
    const int ln = t & 63;        // lane
    const int m0 = blockIdx.y * BM;
    const int n0 = blockIdx.x * BN;
    const int wm = (wv >> 1) * 64;   // wave sub-tile row
    const int wn = (wv & 1) * 64;    // wave sub-tile col

    f32x4 acc[4][4] = {};

    const int lrow = ln >> 3;          // 0..7
    const int lcol = (ln & 7) * 8;     // 0,8,..,56 (ushort)
    const int ldso = wv * 512 + ln * 8;  // per-lane LDS ushort offset in issue block
    const int frow = ln & 15;          // fragment row/col within 16
    const int fko  = (ln >> 4) * 8;    // fragment k offset

    for (int kt = 0; kt < K; kt += BK) {
#pragma unroll
        for (int i = 0; i < 4; ++i) {
            int row = i * 32 + wv * 8 + lrow;
            gload_lds16(A + (size_t)(m0 + row) * K + kt + lcol, As + i * 2048 + ldso);
            gload_lds16(B + (size_t)(n0 + row) * K + kt + lcol, Bs + i * 2048 + ldso);
        }
        __syncthreads();   // compiler drains vmcnt/lgkmcnt before s_barrier

#pragma unroll
        for (int kk = 0; kk < BK; kk += 32) {
            bf16x8 af[4], bfr[4];
#pragma unroll
            for (int f = 0; f < 4; ++f) {
                af[f]  = *reinterpret_cast<const bf16x8*>(As + (wm + f * 16 + frow) * BK + kk + fko);
                bfr[f] = *reinterpret_cast<const bf16x8*>(Bs + (wn + f * 16 + frow) * BK + kk + fko);
            }
#pragma unroll
            for (int fm = 0; fm < 4; ++fm)
#pragma unroll
                for (int fn = 0; fn < 4; ++fn)
                    acc[fm][fn] = __builtin_amdgcn_mfma_f32_16x16x32_bf16(
                        af[fm], bfr[fn], acc[fm][fn], 0, 0, 0);
        }
        __syncthreads();
    }

    // epilogue: C/D layout col=lane&15, row=(lane>>4)*4+reg
#pragma unroll
    for (int fm = 0; fm < 4; ++fm) {
#pragma unroll
        for (int r = 0; r < 4; ++r) {
            int row = m0 + wm + fm * 16 + (ln >> 4) * 4 + r;
            float* crow = C + (size_t)row * N + n0 + wn + (ln & 15);
#pragma unroll
            for (int fn = 0; fn < 4; ++fn)
                crow[fn * 16] = acc[fm][fn][r];
        }
    }
}

// ---------------- launch ----------------

extern "C" void kernel_launch(void* const* d_in, const int* in_sizes, int n_in,
                              void* d_out, int out_size, void* d_ws, size_t ws_size,
                              hipStream_t stream) {
    const float* x  = (const float*)d_in[0];
    const float* c0 = (const float*)d_in[1];
    const float* c1 = (const float*)d_in[2];
    const float* c2 = (const float*)d_in[3];
    float* out = (float*)d_out;

    const int K = 1024;           // input dim
    const int N = 4096;           // OUT_DIM * SUP
    const int M = in_sizes[0] / K;  // tokens = B*S = 4096

    u16* xb = (u16*)d_ws;                          // M*K bf16   (8 MB)
    u16* Wt = (u16*)d_ws + (size_t)M * K;          // N*K bf16   (8 MB)

    conv_x_kernel<<<(M * K) / (256 * 8), 256, 0, stream>>>(x, xb, M * K);
    prep_w_kernel<<<128, 256, 0, stream>>>(c0, c1, c2, Wt);

    dim3 g(N / BN, M / BM);
    gemm_bt_kernel<<<g, 256, 0, stream>>>(xb, Wt, out, M, N, K);
}

// Round 2
// 65.101 us; speedup vs baseline: 1.1541x; 1.1541x over previous
//
#include <hip/hip_runtime.h>
#include <stdint.h>

typedef unsigned short u16;
typedef unsigned int u32;
typedef __bf16 bf16x8 __attribute__((ext_vector_type(8)));
typedef float f32x4 __attribute__((ext_vector_type(4)));

// ---------------- helpers ----------------

__device__ __forceinline__ u16 f2bf(float f) {
    u32 u = __builtin_bit_cast(u32, f);
    u32 r = (u + 0x7FFFu + ((u >> 16) & 1u)) >> 16;
    return (u16)r;
}

__device__ __forceinline__ void gload_lds16(const u16* g, u16* l) {
    __builtin_amdgcn_global_load_lds(
        (const __attribute__((address_space(1))) void*)g,
        (__attribute__((address_space(3))) void*)l,
        16, 0, 0);
}

// ---------------- kernel 1: x fp32 -> bf16 ----------------

__global__ __launch_bounds__(256) void conv_x_kernel(const float* __restrict__ x,
                                                     u16* __restrict__ xb, int nElem) {
    int i = (blockIdx.x * 256 + threadIdx.x) * 8;
    if (i + 8 > nElem) return;
    float4 a = *reinterpret_cast<const float4*>(x + i);
    float4 b = *reinterpret_cast<const float4*>(x + i + 4);
    uint4 pk;
    pk.x = (u32)f2bf(a.x) | ((u32)f2bf(a.y) << 16);
    pk.y = (u32)f2bf(a.z) | ((u32)f2bf(a.w) << 16);
    pk.z = (u32)f2bf(b.x) | ((u32)f2bf(b.y) << 16);
    pk.w = (u32)f2bf(b.z) | ((u32)f2bf(b.w) << 16);
    *reinterpret_cast<uint4*>(xb + i) = pk;
}

// ---------------- kernel 2: fused weight precompute ----------------
// Wt[o*4+s][i] (bf16, [4096][1024]) = sum_{q,r} c0[b,w,q,s]*c1[q,c,x,r,s]*c2[r,d,y,s]
// i=(b*128+c*8+d), o=(w*128+x*8+y).
// grid: 512 blocks = (bc=128) x (part=4); 256 threads.

__global__ __launch_bounds__(256) void prep_w_kernel(const float* __restrict__ c0,
                                                     const float* __restrict__ c1,
                                                     const float* __restrict__ c2,
                                                     u16* __restrict__ Wt) {
    __shared__ float l_c0[256];   // [w][q][s]     (slice at fixed b)
    __shared__ float l_c1[4096];  // [q][x][r][s]  (slice at fixed c)
    __shared__ float l_c2[2048];  // [r][d][y][s]  (full)
    __shared__ float l_w1[4096];  // [w][x][r][s]

    const int t = threadIdx.x;
    const int bc = blockIdx.x >> 2;   // 0..127
    const int part = blockIdx.x & 3;  // 0..3 : w-pair {2p, 2p+1}
    const int b = bc >> 4, c = bc & 15;

    l_c0[t] = c0[b * 256 + t];
#pragma unroll
    for (int q = 0; q < 8; ++q) {
        l_c1[q * 512 + t]       = c1[(q * 16 + c) * 512 + t];
        l_c1[q * 512 + t + 256] = c1[(q * 16 + c) * 512 + t + 256];
    }
#pragma unroll
    for (int j = 0; j < 8; ++j) l_c2[t + 256 * j] = c2[t + 256 * j];
    __syncthreads();

    // W1[w][x][r][s] = sum_q c0[w,q,s] * c1[q,x,r,s]   (only w in {2p,2p+1})
#pragma unroll
    for (int j = 0; j < 4; ++j) {
        int idx = t + 256 * (part * 4 + j);   // ((w*16+x)*8+r)*4+s
        int s = idx & 3;
        int r = (idx >> 2) & 7;
        int x = (idx >> 5) & 15;
        int w = idx >> 9;
        float acc = 0.f;
#pragma unroll
        for (int q = 0; q < 8; ++q)
            acc += l_c0[(w * 8 + q) * 4 + s] * l_c1[q * 512 + (x * 8 + r) * 4 + s];
        l_w1[idx] = acc;
    }
    __syncthreads();

    // Wt[(o*4+s)][b*128+c*8+d] = sum_r W1[w,x,r,s] * c2[r,d,y,s]
#pragma unroll
    for (int j = 0; j < 4; ++j) {
        int idx = t + 256 * (part * 4 + j);   // ((w*16+x)*8+y)*4+s == o*4+s
        int s = idx & 3;
        int y = (idx >> 2) & 7;
        int x = (idx >> 5) & 15;
        int w = idx >> 9;
        float acc[8] = {0.f, 0.f, 0.f, 0.f, 0.f, 0.f, 0.f, 0.f};
#pragma unroll
        for (int r = 0; r < 8; ++r) {
            float w1 = l_w1[((w * 16 + x) * 8 + r) * 4 + s];
#pragma unroll
            for (int d = 0; d < 8; ++d)
                acc[d] += w1 * l_c2[((r * 8 + d) * 8 + y) * 4 + s];
        }
        uint4 pk;
        pk.x = (u32)f2bf(acc[0]) | ((u32)f2bf(acc[1]) << 16);
        pk.y = (u32)f2bf(acc[2]) | ((u32)f2bf(acc[3]) << 16);
        pk.z = (u32)f2bf(acc[4]) | ((u32)f2bf(acc[5]) << 16);
        pk.w = (u32)f2bf(acc[6]) | ((u32)f2bf(acc[7]) << 16);
        *reinterpret_cast<uint4*>(&Wt[(size_t)idx * 1024 + b * 128 + c * 8]) = pk;
    }
}

// ---------------- kernel 3: 256x256 deep-pipelined GEMM ----------------
// C[M][N] = A[M][K] * B[N][K]^T.  A = xb [4096][1024] bf16, B = Wt [4096][1024] bf16.
// 512 threads = 8 waves (2M x 4N); per-wave output 128x64 (8x4 frags of 16x16).
// K split into BKT=32 subtiles; 4 LDS tile-buffers (128 KiB), prefetch depth 3,
// steady-state wait vmcnt(8) (never 0). 2 phases/subtile of 16 MFMA, setprio-wrapped.
// LDS swizzle: physical kslot' = kslot ^ (row&3), applied via pre-swizzled global
// source (linear global_load_lds dest) + swizzled ds_read address.

#define BKT 32
#define TBUF_U16 8192   // 256 rows * 32 k (u16) = 16 KB per tile-buffer

__global__ __launch_bounds__(512, 2) void gemm256_kernel(const u16* __restrict__ A,
                                                         const u16* __restrict__ B,
                                                         float* __restrict__ C,
                                                         int M, int N, int K) {
    __shared__ u16 As[4 * TBUF_U16];  // 64 KB
    __shared__ u16 Bs[4 * TBUF_U16];  // 64 KB

    const int t  = threadIdx.x;
    const int ln = t & 63;
    const int wid = t >> 6;          // 0..7
    const int wr = wid >> 2;         // 0..1  -> M offset wr*128
    const int wc = wid & 3;          // 0..3  -> N offset wc*64
    const int m0 = blockIdx.y * 256;
    const int n0 = blockIdx.x * 256;
    const int NT = K >> 5;           // 32 subtiles

    // staging decomposition for one gload instruction (512 thr * 16B = 128 rows):
    const int sr = t >> 2;                      // local row 0..127
    const int ss = (t & 3) ^ (sr & 3);          // logical kslot fetched (pre-swizzle)
    const int sdst = t * 8;                     // linear LDS dest (u16)

    // ds_read fragment addressing
    const int frow = ln & 15;
    const int ks   = ln >> 4;                   // logical kslot 0..3

    f32x4 acc[8][4] = {};

    // ---- prologue: stage subtiles 0,1,2 into buffers 0,1,2 ----
#pragma unroll
    for (int tt = 0; tt < 3; ++tt) {
#pragma unroll
        for (int j = 0; j < 2; ++j) {
            gload_lds16(A + (size_t)(m0 + j * 128 + sr) * K + tt * BKT + ss * 8,
                        As + tt * TBUF_U16 + j * 4096 + sdst);
            gload_lds16(B + (size_t)(n0 + j * 128 + sr) * K + tt * BKT + ss * 8,
                        Bs + tt * TBUF_U16 + j * 4096 + sdst);
        }
    }
    asm volatile("s_waitcnt vmcnt(8)" ::: "memory");   // subtile 0 resident
    __builtin_amdgcn_sched_barrier(0);
    __builtin_amdgcn_s_barrier();

    for (int tt = 0; tt < NT; ++tt) {
        const u16* Ab = As + (tt & 3) * TBUF_U16;
        const u16* Bb = Bs + (tt & 3) * TBUF_U16;
        const int b3 = ((tt + 3) & 3) * TBUF_U16;
        const bool pf = (tt + 3) < NT;
        const int kt3 = (tt + 3) * BKT;

        // ======== phase 0: quadrant fm 0..3, all fn ========
        bf16x8 af[4], bfr[4];
#pragma unroll
        for (int f = 0; f < 4; ++f) {
            int ar = wr * 128 + f * 16 + frow;
            af[f] = *reinterpret_cast<const bf16x8*>(Ab + ar * 32 + ((ks ^ (ar & 3)) * 8));
            int br = wc * 64 + f * 16 + frow;
            bfr[f] = *reinterpret_cast<const bf16x8*>(Bb + br * 32 + ((ks ^ (br & 3)) * 8));
        }
        if (pf) {   // stage A of subtile tt+3
            gload_lds16(A + (size_t)(m0 + sr) * K + kt3 + ss * 8,       As + b3 + sdst);
            gload_lds16(A + (size_t)(m0 + 128 + sr) * K + kt3 + ss * 8, As + b3 + 4096 + sdst);
        }
        __builtin_amdgcn_s_barrier();
        asm volatile("s_waitcnt lgkmcnt(0)" ::: "memory");
        __builtin_amdgcn_sched_barrier(0);
        __builtin_amdgcn_s_setprio(1);
#pragma unroll
        for (int fm = 0; fm < 4; ++fm)
#pragma unroll
            for (int fn = 0; fn < 4; ++fn)
                acc[fm][fn] = __builtin_amdgcn_mfma_f32_16x16x32_bf16(
                    af[fm], bfr[fn], acc[fm][fn], 0, 0, 0);
        __builtin_amdgcn_s_setprio(0);
        __builtin_amdgcn_s_barrier();

        // ======== phase 1: quadrant fm 4..7, all fn (B frags reused) ========
        bf16x8 af2[4];
#pragma unroll
        for (int f = 0; f < 4; ++f) {
            int ar = wr * 128 + (f + 4) * 16 + frow;
            af2[f] = *reinterpret_cast<const bf16x8*>(Ab + ar * 32 + ((ks ^ (ar & 3)) * 8));
        }
        if (pf) {   // stage B of subtile tt+3
            gload_lds16(B + (size_t)(n0 + sr) * K + kt3 + ss * 8,       Bs + b3 + sdst);
            gload_lds16(B + (size_t)(n0 + 128 + sr) * K + kt3 + ss * 8, Bs + b3 + 4096 + sdst);
        }
        __builtin_amdgcn_s_barrier();
        asm volatile("s_waitcnt lgkmcnt(0)" ::: "memory");
        __builtin_amdgcn_sched_barrier(0);
        __builtin_amdgcn_s_setprio(1);
#pragma unroll
        for (int fm = 0; fm < 4; ++fm)
#pragma unroll
            for (int fn = 0; fn < 4; ++fn)
                acc[fm + 4][fn] = __builtin_amdgcn_mfma_f32_16x16x32_bf16(
                    af2[fm], bfr[fn], acc[fm + 4][fn], 0, 0, 0);
        __builtin_amdgcn_s_setprio(0);

        // ---- end-of-subtile: counted vmcnt (tt+1's 4 loads must be resident) ----
        if (tt < NT - 3) {
            asm volatile("s_waitcnt vmcnt(8)" ::: "memory");
        } else if (tt == NT - 3) {
            asm volatile("s_waitcnt vmcnt(4)" ::: "memory");
        } else if (tt == NT - 2) {
            asm volatile("s_waitcnt vmcnt(0)" ::: "memory");
        }
        __builtin_amdgcn_sched_barrier(0);
        __builtin_amdgcn_s_barrier();
    }

    // ---- epilogue: C/D layout col=lane&15, row=(lane>>4)*4+reg ----
    const int cr = (ln >> 4) * 4;
    const int cc = ln & 15;
#pragma unroll
    for (int fm = 0; fm < 8; ++fm) {
#pragma unroll
        for (int r = 0; r < 4; ++r) {
            int row = m0 + wr * 128 + fm * 16 + cr + r;
            float* p = C + (size_t)row * N + n0 + wc * 64 + cc;
#pragma unroll
            for (int fn = 0; fn < 4; ++fn)
                p[fn * 16] = acc[fm][fn][r];
        }
    }
}

// ---------------- launch ----------------

extern "C" void kernel_launch(void* const* d_in, const int* in_sizes, int n_in,
                              void* d_out, int out_size, void* d_ws, size_t ws_size,
                              hipStream_t stream) {
    const float* x  = (const float*)d_in[0];
    const float* c0 = (const float*)d_in[1];
    const float* c1 = (const float*)d_in[2];
    const float* c2 = (const float*)d_in[3];
    float* out = (float*)d_out;

    const int K = 1024;             // input dim
    const int N = 4096;             // OUT_DIM * SUP
    const int M = in_sizes[0] / K;  // tokens = B*S

    u16* xb = (u16*)d_ws;                        // M*K bf16
    u16* Wt = (u16*)d_ws + (size_t)M * K;        // N*K bf16

    conv_x_kernel<<<(M * K) / (256 * 8), 256, 0, stream>>>(x, xb, M * K);
    prep_w_kernel<<<512, 256, 0, stream>>>(c0, c1, c2, Wt);

    dim3 g(N / 256, M / 256);
    gemm256_kernel<<<g, 512, 0, stream>>>(xb, Wt, out, M, N, K);
}

// Round 4
// 63.568 us; speedup vs baseline: 1.1820x; 1.0241x over previous
//
#include <hip/hip_runtime.h>
#include <stdint.h>

typedef unsigned short u16;
typedef unsigned int u32;
typedef __bf16 bf16x8 __attribute__((ext_vector_type(8)));
typedef float f32x4 __attribute__((ext_vector_type(4)));

// ---------------- helpers ----------------

__device__ __forceinline__ u16 f2bf(float f) {
    u32 u = __builtin_bit_cast(u32, f);
    u32 r = (u + 0x7FFFu + ((u >> 16) & 1u)) >> 16;
    return (u16)r;
}

__device__ __forceinline__ void gload_lds16(const u16* g, u16* l) {
    __builtin_amdgcn_global_load_lds(
        (const __attribute__((address_space(1))) void*)g,
        (__attribute__((address_space(3))) void*)l,
        16, 0, 0);
}

// ---------------- kernel 1: x fp32 -> bf16 ----------------

__global__ __launch_bounds__(256) void conv_x_kernel(const float* __restrict__ x,
                                                     u16* __restrict__ xb, int nElem) {
    int i = (blockIdx.x * 256 + threadIdx.x) * 8;
    if (i + 8 > nElem) return;
    float4 a = *reinterpret_cast<const float4*>(x + i);
    float4 b = *reinterpret_cast<const float4*>(x + i + 4);
    uint4 pk;
    pk.x = (u32)f2bf(a.x) | ((u32)f2bf(a.y) << 16);
    pk.y = (u32)f2bf(a.z) | ((u32)f2bf(a.w) << 16);
    pk.z = (u32)f2bf(b.x) | ((u32)f2bf(b.y) << 16);
    pk.w = (u32)f2bf(b.z) | ((u32)f2bf(b.w) << 16);
    *reinterpret_cast<uint4*>(xb + i) = pk;
}

// ---------------- kernel 2: fused weight precompute ----------------
// Wt[o*4+s][i] (bf16, [4096][1024]) = sum_{q,r} c0[b,w,q,s]*c1[q,c,x,r,s]*c2[r,d,y,s]
// i=(b*128+c*8+d), o=(w*128+x*8+y).
// grid: 512 blocks = (bc=128) x (part=4); 256 threads.

__global__ __launch_bounds__(256) void prep_w_kernel(const float* __restrict__ c0,
                                                     const float* __restrict__ c1,
                                                     const float* __restrict__ c2,
                                                     u16* __restrict__ Wt) {
    __shared__ float l_c0[256];   // [w][q][s]     (slice at fixed b)
    __shared__ float l_c1[4096];  // [q][x][r][s]  (slice at fixed c)
    __shared__ float l_c2[2048];  // [r][d][y][s]  (full)
    __shared__ float l_w1[4096];  // [w][x][r][s]

    const int t = threadIdx.x;
    const int bc = blockIdx.x >> 2;   // 0..127
    const int part = blockIdx.x & 3;  // 0..3 : w-pair {2p, 2p+1}
    const int b = bc >> 4, c = bc & 15;

    l_c0[t] = c0[b * 256 + t];
#pragma unroll
    for (int q = 0; q < 8; ++q) {
        l_c1[q * 512 + t]       = c1[(q * 16 + c) * 512 + t];
        l_c1[q * 512 + t + 256] = c1[(q * 16 + c) * 512 + t + 256];
    }
#pragma unroll
    for (int j = 0; j < 8; ++j) l_c2[t + 256 * j] = c2[t + 256 * j];
    __syncthreads();

    // W1[w][x][r][s] = sum_q c0[w,q,s] * c1[q,x,r,s]   (only w in {2p,2p+1})
#pragma unroll
    for (int j = 0; j < 4; ++j) {
        int idx = t + 256 * (part * 4 + j);   // ((w*16+x)*8+r)*4+s
        int s = idx & 3;
        int r = (idx >> 2) & 7;
        int x = (idx >> 5) & 15;
        int w = idx >> 9;
        float acc = 0.f;
#pragma unroll
        for (int q = 0; q < 8; ++q)
            acc += l_c0[(w * 8 + q) * 4 + s] * l_c1[q * 512 + (x * 8 + r) * 4 + s];
        l_w1[idx] = acc;
    }
    __syncthreads();

    // Wt[(o*4+s)][b*128+c*8+d] = sum_r W1[w,x,r,s] * c2[r,d,y,s]
#pragma unroll
    for (int j = 0; j < 4; ++j) {
        int idx = t + 256 * (part * 4 + j);   // ((w*16+x)*8+y)*4+s == o*4+s
        int s = idx & 3;
        int y = (idx >> 2) & 7;
        int x = (idx >> 5) & 15;
        int w = idx >> 9;
        float acc[8] = {0.f, 0.f, 0.f, 0.f, 0.f, 0.f, 0.f, 0.f};
#pragma unroll
        for (int r = 0; r < 8; ++r) {
            float w1 = l_w1[((w * 16 + x) * 8 + r) * 4 + s];
#pragma unroll
            for (int d = 0; d < 8; ++d)
                acc[d] += w1 * l_c2[((r * 8 + d) * 8 + y) * 4 + s];
        }
        uint4 pk;
        pk.x = (u32)f2bf(acc[0]) | ((u32)f2bf(acc[1]) << 16);
        pk.y = (u32)f2bf(acc[2]) | ((u32)f2bf(acc[3]) << 16);
        pk.z = (u32)f2bf(acc[4]) | ((u32)f2bf(acc[5]) << 16);
        pk.w = (u32)f2bf(acc[6]) | ((u32)f2bf(acc[7]) << 16);
        *reinterpret_cast<uint4*>(&Wt[(size_t)idx * 1024 + b * 128 + c * 8]) = pk;
    }
}

// ---------------- kernel 3: 256x256 deep-pipelined GEMM ----------------
// C[M][N] = A[M][K] * B[N][K]^T.  A = xb [4096][1024] bf16, B = Wt [4096][1024] bf16.
// 512 threads = 8 waves (2M x 4N); per-wave output 128x64 (8x4 frags of 16x16).
// K split into BKT=32 subtiles; 4 LDS tile-buffers (128 KiB), prefetch depth 3,
// steady-state wait vmcnt(8) (never 0). 2 phases/subtile of 16 MFMA, setprio-wrapped.
//
// LDS swizzle (bank math): row stride 64B so bank = ((row&1)<<4)|(slot<<2)|dword.
// phys_slot = logical_ks ^ ((row>>1)&3): 16 consecutive rows sweep all 8
// (row&1, slot) combos -> 2 lanes/bank-group -> conflict-free (2-way is free).
// Applied as pre-swizzled GLOBAL source (linear global_load_lds dest) + the
// same XOR on the ds_read address (both-sides involution).

#define BKT 32
#define TBUF_U16 8192   // 256 rows * 32 k (u16) = 16 KB per tile-buffer

__global__ __launch_bounds__(512, 2) void gemm256_kernel(const u16* __restrict__ A,
                                                         const u16* __restrict__ B,
                                                         float* __restrict__ C,
                                                         int M, int N, int K) {
    __shared__ u16 As[4 * TBUF_U16];  // 64 KB
    __shared__ u16 Bs[4 * TBUF_U16];  // 64 KB

    const int t  = threadIdx.x;
    const int ln = t & 63;
    const int wid = t >> 6;          // 0..7
    const int wr = wid >> 2;         // 0..1  -> M offset wr*128
    const int wc = wid & 3;          // 0..3  -> N offset wc*64
    const int m0 = blockIdx.y * 256;
    const int n0 = blockIdx.x * 256;
    const int NT = K >> 5;           // 32 subtiles

    // staging decomposition for one gload instruction (512 thr * 16B = 128 rows):
    const int sr = t >> 2;                           // local row 0..127
    const int ss = (t & 3) ^ ((sr >> 1) & 3);        // logical kslot fetched (pre-swizzle)
    const int sdst = t * 8;                          // linear LDS dest (u16)

    // ds_read fragment addressing
    const int frow = ln & 15;
    const int ks   = ln >> 4;                        // logical kslot 0..3

    f32x4 acc[8][4] = {};

    // ---- prologue: stage subtiles 0,1,2 into buffers 0,1,2 ----
#pragma unroll
    for (int tt = 0; tt < 3; ++tt) {
#pragma unroll
        for (int j = 0; j < 2; ++j) {
            gload_lds16(A + (size_t)(m0 + j * 128 + sr) * K + tt * BKT + ss * 8,
                        As + tt * TBUF_U16 + j * 4096 + sdst);
            gload_lds16(B + (size_t)(n0 + j * 128 + sr) * K + tt * BKT + ss * 8,
                        Bs + tt * TBUF_U16 + j * 4096 + sdst);
        }
    }
    asm volatile("s_waitcnt vmcnt(8)" ::: "memory");   // subtile 0 resident
    __builtin_amdgcn_sched_barrier(0);
    __builtin_amdgcn_s_barrier();

    for (int tt = 0; tt < NT; ++tt) {
        const u16* Ab = As + (tt & 3) * TBUF_U16;
        const u16* Bb = Bs + (tt & 3) * TBUF_U16;
        const int b3 = ((tt + 3) & 3) * TBUF_U16;
        const bool pf = (tt + 3) < NT;
        const int kt3 = (tt + 3) * BKT;

        // ======== phase 0: quadrant fm 0..3, all fn ========
        bf16x8 af[4], bfr[4];
#pragma unroll
        for (int f = 0; f < 4; ++f) {
            int ar = wr * 128 + f * 16 + frow;
            af[f] = *reinterpret_cast<const bf16x8*>(Ab + ar * 32 + ((ks ^ ((ar >> 1) & 3)) * 8));
            int br = wc * 64 + f * 16 + frow;
            bfr[f] = *reinterpret_cast<const bf16x8*>(Bb + br * 32 + ((ks ^ ((br >> 1) & 3)) * 8));
        }
        if (pf) {   // stage A of subtile tt+3
            gload_lds16(A + (size_t)(m0 + sr) * K + kt3 + ss * 8,       As + b3 + sdst);
            gload_lds16(A + (size_t)(m0 + 128 + sr) * K + kt3 + ss * 8, As + b3 + 4096 + sdst);
        }
        __builtin_amdgcn_s_barrier();
        asm volatile("s_waitcnt lgkmcnt(0)" ::: "memory");
        __builtin_amdgcn_sched_barrier(0);
        __builtin_amdgcn_s_setprio(1);
#pragma unroll
        for (int fm = 0; fm < 4; ++fm)
#pragma unroll
            for (int fn = 0; fn < 4; ++fn)
                acc[fm][fn] = __builtin_amdgcn_mfma_f32_16x16x32_bf16(
                    af[fm], bfr[fn], acc[fm][fn], 0, 0, 0);
        __builtin_amdgcn_s_setprio(0);
        __builtin_amdgcn_s_barrier();

        // ======== phase 1: quadrant fm 4..7, all fn (B frags reused) ========
        bf16x8 af2[4];
#pragma unroll
        for (int f = 0; f < 4; ++f) {
            int ar = wr * 128 + (f + 4) * 16 + frow;
            af2[f] = *reinterpret_cast<const bf16x8*>(Ab + ar * 32 + ((ks ^ ((ar >> 1) & 3)) * 8));
        }
        if (pf) {   // stage B of subtile tt+3
            gload_lds16(B + (size_t)(n0 + sr) * K + kt3 + ss * 8,       Bs + b3 + sdst);
            gload_lds16(B + (size_t)(n0 + 128 + sr) * K + kt3 + ss * 8, Bs + b3 + 4096 + sdst);
        }
        __builtin_amdgcn_s_barrier();
        asm volatile("s_waitcnt lgkmcnt(0)" ::: "memory");
        __builtin_amdgcn_sched_barrier(0);
        __builtin_amdgcn_s_setprio(1);
#pragma unroll
        for (int fm = 0; fm < 4; ++fm)
#pragma unroll
            for (int fn = 0; fn < 4; ++fn)
                acc[fm + 4][fn] = __builtin_amdgcn_mfma_f32_16x16x32_bf16(
                    af2[fm], bfr[fn], acc[fm + 4][fn], 0, 0, 0);
        __builtin_amdgcn_s_setprio(0);

        // ---- end-of-subtile: counted vmcnt (tt+1's 4 loads must be resident) ----
        if (tt < NT - 3) {
            asm volatile("s_waitcnt vmcnt(8)" ::: "memory");
        } else if (tt == NT - 3) {
            asm volatile("s_waitcnt vmcnt(4)" ::: "memory");
        } else if (tt == NT - 2) {
            asm volatile("s_waitcnt vmcnt(0)" ::: "memory");
        }
        __builtin_amdgcn_sched_barrier(0);
        __builtin_amdgcn_s_barrier();
    }

    // ---- epilogue: C/D layout col=lane&15, row=(lane>>4)*4+reg ----
    const int cr = (ln >> 4) * 4;
    const int cc = ln & 15;
#pragma unroll
    for (int fm = 0; fm < 8; ++fm) {
#pragma unroll
        for (int r = 0; r < 4; ++r) {
            int row = m0 + wr * 128 + fm * 16 + cr + r;
            float* p = C + (size_t)row * N + n0 + wc * 64 + cc;
#pragma unroll
            for (int fn = 0; fn < 4; ++fn)
                p[fn * 16] = acc[fm][fn][r];
        }
    }
}

// ---------------- launch ----------------

extern "C" void kernel_launch(void* const* d_in, const int* in_sizes, int n_in,
                              void* d_out, int out_size, void* d_ws, size_t ws_size,
                              hipStream_t stream) {
    const float* x  = (const float*)d_in[0];
    const float* c0 = (const float*)d_in[1];
    const float* c1 = (const float*)d_in[2];
    const float* c2 = (const float*)d_in[3];
    float* out = (float*)d_out;

    const int K = 1024;             // input dim
    const int N = 4096;             // OUT_DIM * SUP
    const int M = in_sizes[0] / K;  // tokens = B*S

    u16* xb = (u16*)d_ws;                        // M*K bf16
    u16* Wt = (u16*)d_ws + (size_t)M * K;        // N*K bf16

    conv_x_kernel<<<(M * K) / (256 * 8), 256, 0, stream>>>(x, xb, M * K);
    prep_w_kernel<<<512, 256, 0, stream>>>(c0, c1, c2, Wt);

    dim3 g(N / 256, M / 256);
    gemm256_kernel<<<g, 512, 0, stream>>>(xb, Wt, out, M, N, K);
}

// Round 5
// 58.401 us; speedup vs baseline: 1.2865x; 1.0885x over previous
//
#include <hip/hip_runtime.h>
#include <stdint.h>

typedef unsigned short u16;
typedef unsigned int u32;
typedef __bf16 bf16x8 __attribute__((ext_vector_type(8)));
typedef float f32x4 __attribute__((ext_vector_type(4)));

#define MFMA16 __builtin_amdgcn_mfma_f32_16x16x32_bf16

// ---------------- helpers ----------------

__device__ __forceinline__ u16 f2bf(float f) {
    u32 u = __builtin_bit_cast(u32, f);
    u32 r = (u + 0x7FFFu + ((u >> 16) & 1u)) >> 16;
    return (u16)r;
}

__device__ __forceinline__ void gload_lds16(const u16* g, u16* l) {
    __builtin_amdgcn_global_load_lds(
        (const __attribute__((address_space(1))) void*)g,
        (__attribute__((address_space(3))) void*)l,
        16, 0, 0);
}

// ================= kernel 1: merged conv_x + prep_w =================
// blocks [0, convBlocks): x fp32 -> bf16 (8 elems/thread).
// blocks [convBlocks, convBlocks+512): fused TT weight precompute ->
//   Wt[o*4+s][i] (bf16 [4096][1024]) = sum_{q,r} c0[b,w,q,s]*c1[q,c,x,r,s]*c2[r,d,y,s]
//   i=(b*128+c*8+d), o=(w*128+x*8+y); 512 blocks = (bc=128)x(part=4).

__global__ __launch_bounds__(256) void pre_kernel(const float* __restrict__ x,
                                                  const float* __restrict__ c0,
                                                  const float* __restrict__ c1,
                                                  const float* __restrict__ c2,
                                                  u16* __restrict__ xb,
                                                  u16* __restrict__ Wt,
                                                  int convBlocks, int nElem) {
    __shared__ float smem[10496];   // 41 KB: c0(256) c1(4096) c2(2048) w1(4096)
    const int t = threadIdx.x;

    if ((int)blockIdx.x < convBlocks) {
        int i = (blockIdx.x * 256 + t) * 8;
        if (i + 8 > nElem) return;
        float4 a = *reinterpret_cast<const float4*>(x + i);
        float4 b = *reinterpret_cast<const float4*>(x + i + 4);
        uint4 pk;
        pk.x = (u32)f2bf(a.x) | ((u32)f2bf(a.y) << 16);
        pk.y = (u32)f2bf(a.z) | ((u32)f2bf(a.w) << 16);
        pk.z = (u32)f2bf(b.x) | ((u32)f2bf(b.y) << 16);
        pk.w = (u32)f2bf(b.z) | ((u32)f2bf(b.w) << 16);
        *reinterpret_cast<uint4*>(xb + i) = pk;
        return;
    }

    float* l_c0 = smem;           // [w][q][s]     (slice at fixed b)
    float* l_c1 = smem + 256;     // [q][x][r][s]  (slice at fixed c)
    float* l_c2 = smem + 4352;    // [r][d][y][s]  (full)
    float* l_w1 = smem + 6400;    // [w][x][r][s]

    const int bid = blockIdx.x - convBlocks;
    const int bc = bid >> 2;      // 0..127
    const int part = bid & 3;     // 0..3 : w-pair {2p, 2p+1}
    const int b = bc >> 4, c = bc & 15;

    l_c0[t] = c0[b * 256 + t];
#pragma unroll
    for (int q = 0; q < 8; ++q) {
        l_c1[q * 512 + t]       = c1[(q * 16 + c) * 512 + t];
        l_c1[q * 512 + t + 256] = c1[(q * 16 + c) * 512 + t + 256];
    }
#pragma unroll
    for (int j = 0; j < 8; ++j) l_c2[t + 256 * j] = c2[t + 256 * j];
    __syncthreads();

    // W1[w][x][r][s] = sum_q c0[w,q,s] * c1[q,x,r,s]   (only w in {2p,2p+1})
#pragma unroll
    for (int j = 0; j < 4; ++j) {
        int idx = t + 256 * (part * 4 + j);   // ((w*16+x)*8+r)*4+s
        int s = idx & 3;
        int r = (idx >> 2) & 7;
        int xx = (idx >> 5) & 15;
        int w = idx >> 9;
        float acc = 0.f;
#pragma unroll
        for (int q = 0; q < 8; ++q)
            acc += l_c0[(w * 8 + q) * 4 + s] * l_c1[q * 512 + (xx * 8 + r) * 4 + s];
        l_w1[idx] = acc;
    }
    __syncthreads();

    // Wt[(o*4+s)][b*128+c*8+d] = sum_r W1[w,x,r,s] * c2[r,d,y,s]
#pragma unroll
    for (int j = 0; j < 4; ++j) {
        int idx = t + 256 * (part * 4 + j);   // ((w*16+x)*8+y)*4+s == o*4+s
        int s = idx & 3;
        int y = (idx >> 2) & 7;
        int xx = (idx >> 5) & 15;
        int w = idx >> 9;
        float acc[8] = {0.f, 0.f, 0.f, 0.f, 0.f, 0.f, 0.f, 0.f};
#pragma unroll
        for (int r = 0; r < 8; ++r) {
            float w1 = l_w1[((w * 16 + xx) * 8 + r) * 4 + s];
#pragma unroll
            for (int d = 0; d < 8; ++d)
                acc[d] += w1 * l_c2[((r * 8 + d) * 8 + y) * 4 + s];
        }
        uint4 pk;
        pk.x = (u32)f2bf(acc[0]) | ((u32)f2bf(acc[1]) << 16);
        pk.y = (u32)f2bf(acc[2]) | ((u32)f2bf(acc[3]) << 16);
        pk.z = (u32)f2bf(acc[4]) | ((u32)f2bf(acc[5]) << 16);
        pk.w = (u32)f2bf(acc[6]) | ((u32)f2bf(acc[7]) << 16);
        *reinterpret_cast<uint4*>(&Wt[(size_t)idx * 1024 + b * 128 + c * 8]) = pk;
    }
}

// ================= kernel 2: 256x256 BK=64 8-phase GEMM =================
// C[M][N] = A[M][K] * B[N][K]^T.  A = xb, B = Wt (both bf16 [4096][1024]).
// 512 threads = 8 waves (2M x 4N); per-wave output 128x64 = acc[8][4] 16x16 frags.
// K-tile = BK=64; LDS = 2 dbuf slots x (A[256][64] + B[256][64]) = 128 KiB.
// 4 phases per K-tile, 16 MFMA each (f-pair x 4 n x 2 k-halves); B frags loaded
// once per K-tile (phase 0) and held in regs across all 4 phases.
// Staging of K-tile kt+1: B halves in ph0, A halves in ph1 (4 gloads each);
// single wait at ph3-end: vmcnt(0) with NOTHING younger outstanding (kt+2's
// staging starts only at kt+1.ph0), so it waits exactly the needed loads;
// flight time 2.2-3.2 phases >= L2/L3 latency.
//
// LDS swizzle (row stride 128 B = 32 dwords -> wraps all 32 banks): 16-B chunk
// slot (0..7) phys = logical ^ (row&7). ds_read: 16 lanes/quad read 16 rows at
// one logical slot -> spread over 8 slots, 2-way = free. Both-sides involution:
// linear global_load_lds dest + pre-swizzled global source column.

#define SLOT_U16 16384   // one dbuf slot of A (or B): 256 rows * 64 u16
#define HALF_U16 8192    // half-tile: 128 rows * 64 u16

#define BAR() __builtin_amdgcn_s_barrier()
#define LGKM0() do { asm volatile("s_waitcnt lgkmcnt(0)" ::: "memory"); \
                     __builtin_amdgcn_sched_barrier(0); } while (0)
#define VMW0() do { asm volatile("s_waitcnt vmcnt(0)" ::: "memory"); \
                    __builtin_amdgcn_sched_barrier(0); } while (0)

__global__ __launch_bounds__(512, 2) void gemm256_kernel(const u16* __restrict__ A,
                                                         const u16* __restrict__ B,
                                                         float* __restrict__ C,
                                                         int M, int N, int K) {
    __shared__ u16 As[2 * SLOT_U16];  // 64 KB
    __shared__ u16 Bs[2 * SLOT_U16];  // 64 KB

    const int t   = threadIdx.x;
    const int ln  = t & 63;
    const int wid = t >> 6;          // 0..7
    const int wr  = wid >> 2;        // 0..1 -> M offset wr*128
    const int wc  = wid & 3;         // 0..3 -> N offset wc*64
    const int m0  = blockIdx.y * 256;
    const int n0  = blockIdx.x * 256;
    const int NT  = K >> 6;          // 16 K-tiles

    // fragment addressing: row = base + frow; row&7 == ln&7 for all frags.
    const int frow  = ln & 15;
    const int arow  = wr * 128 + frow;
    const int brow  = wc * 64 + frow;
    const int koff0 = (((ln >> 4) ^ (ln & 7)) * 8);  // phys slot * 8 u16, k-half 0
    const int koff1 = koff0 ^ 32;                    // k-half 1 (slot ^ 4)

    // staging: half-tile = 1024 chunks of 16 B; thread t does chunks t, t+512.
    const int ca = t, cb = t + 512;
    const int pra = ca >> 3, lsa = (ca & 7) ^ ((ca >> 3) & 7);
    const int prb = cb >> 3, lsb = (cb & 7) ^ ((cb >> 3) & 7);

    f32x4 acc[8][4] = {};

    auto stage_half = [&](const u16* g /* global row0 of half at tile k-col */,
                          u16* l /* LDS half base */) {
        gload_lds16(g + (size_t)pra * K + lsa * 8, l + ca * 8);
        gload_lds16(g + (size_t)prb * K + lsb * 8, l + cb * 8);
    };

    // ---- prologue: stage all 4 halves of K-tile 0 into slot 0 ----
    stage_half(B + (size_t)n0 * K,          Bs);
    stage_half(B + (size_t)(n0 + 128) * K,  Bs + HALF_U16);
    stage_half(A + (size_t)m0 * K,          As);
    stage_half(A + (size_t)(m0 + 128) * K,  As + HALF_U16);
    VMW0();
    BAR();

    for (int kt = 0; kt < NT; ++kt) {
        const u16* Ab = As + (kt & 1) * SLOT_U16;
        const u16* Bb = Bs + (kt & 1) * SLOT_U16;
        u16* An = As + ((kt + 1) & 1) * SLOT_U16;
        u16* Bn = Bs + ((kt + 1) & 1) * SLOT_U16;
        const bool pf = (kt + 1) < NT;
        const int kc = (kt + 1) * 64;

        bf16x8 bf[4][2];
        bf16x8 a0k0, a0k1, a1k0, a1k1;

#define LOAD_A_PAIR(R0, R1)                                                  \
        {   const u16* ap0 = Ab + (size_t)(arow + (R0)) * 64;                \
            const u16* ap1 = Ab + (size_t)(arow + (R1)) * 64;                \
            a0k0 = *reinterpret_cast<const bf16x8*>(ap0 + koff0);            \
            a0k1 = *reinterpret_cast<const bf16x8*>(ap0 + koff1);            \
            a1k0 = *reinterpret_cast<const bf16x8*>(ap1 + koff0);            \
            a1k1 = *reinterpret_cast<const bf16x8*>(ap1 + koff1);  }

#define MFMA_PAIR(F0, F1)                                                    \
        _Pragma("unroll")                                                    \
        for (int n = 0; n < 4; ++n) {                                        \
            acc[F0][n] = MFMA16(a0k0, bf[n][0], acc[F0][n], 0, 0, 0);        \
            acc[F0][n] = MFMA16(a0k1, bf[n][1], acc[F0][n], 0, 0, 0);        \
            acc[F1][n] = MFMA16(a1k0, bf[n][0], acc[F1][n], 0, 0, 0);        \
            acc[F1][n] = MFMA16(a1k1, bf[n][1], acc[F1][n], 0, 0, 0);        \
        }

        // ======== phase 0: B frags + A f0,f1; stage next B ========
#pragma unroll
        for (int n = 0; n < 4; ++n) {
            const u16* bp = Bb + (size_t)(brow + n * 16) * 64;
            bf[n][0] = *reinterpret_cast<const bf16x8*>(bp + koff0);
            bf[n][1] = *reinterpret_cast<const bf16x8*>(bp + koff1);
        }
        LOAD_A_PAIR(0, 16);
        if (pf) {
            stage_half(B + (size_t)n0 * K + kc,         Bn);
            stage_half(B + (size_t)(n0 + 128) * K + kc, Bn + HALF_U16);
        }
        BAR();
        LGKM0();
        __builtin_amdgcn_s_setprio(1);
        MFMA_PAIR(0, 1);
        __builtin_amdgcn_s_setprio(0);
        BAR();

        // ======== phase 1: A f2,f3; stage next A ========
        LOAD_A_PAIR(32, 48);
        if (pf) {
            stage_half(A + (size_t)m0 * K + kc,         An);
            stage_half(A + (size_t)(m0 + 128) * K + kc, An + HALF_U16);
        }
        BAR();
        LGKM0();
        __builtin_amdgcn_s_setprio(1);
        MFMA_PAIR(2, 3);
        __builtin_amdgcn_s_setprio(0);
        BAR();

        // ======== phase 2: A f4,f5 ========
        LOAD_A_PAIR(64, 80);
        BAR();
        LGKM0();
        __builtin_amdgcn_s_setprio(1);
        MFMA_PAIR(4, 5);
        __builtin_amdgcn_s_setprio(0);
        BAR();

        // ======== phase 3: A f6,f7; wait next tile's loads ========
        LOAD_A_PAIR(96, 112);
        BAR();
        LGKM0();
        __builtin_amdgcn_s_setprio(1);
        MFMA_PAIR(6, 7);
        __builtin_amdgcn_s_setprio(0);
        if (pf) VMW0();   // exactly kt+1's 8 loads outstanding; nothing younger
        BAR();

#undef LOAD_A_PAIR
#undef MFMA_PAIR
    }

    // ---- epilogue: C/D layout col=lane&15, row=(lane>>4)*4+reg ----
    const int cr = (ln >> 4) * 4;
    const int cc = ln & 15;
#pragma unroll
    for (int fm = 0; fm < 8; ++fm) {
#pragma unroll
        for (int r = 0; r < 4; ++r) {
            int row = m0 + wr * 128 + fm * 16 + cr + r;
            float* p = C + (size_t)row * N + n0 + wc * 64 + cc;
#pragma unroll
            for (int fn = 0; fn < 4; ++fn)
                p[fn * 16] = acc[fm][fn][r];
        }
    }
}

// ---------------- launch ----------------

extern "C" void kernel_launch(void* const* d_in, const int* in_sizes, int n_in,
                              void* d_out, int out_size, void* d_ws, size_t ws_size,
                              hipStream_t stream) {
    const float* x  = (const float*)d_in[0];
    const float* c0 = (const float*)d_in[1];
    const float* c1 = (const float*)d_in[2];
    const float* c2 = (const float*)d_in[3];
    float* out = (float*)d_out;

    const int K = 1024;             // input dim
    const int N = 4096;             // OUT_DIM * SUP
    const int M = in_sizes[0] / K;  // tokens = B*S

    u16* xb = (u16*)d_ws;                        // M*K bf16
    u16* Wt = (u16*)d_ws + (size_t)M * K;        // N*K bf16

    const int convBlocks = (M * K) / (256 * 8);
    pre_kernel<<<convBlocks + 512, 256, 0, stream>>>(x, c0, c1, c2, xb, Wt,
                                                     convBlocks, M * K);

    dim3 g(N / 256, M / 256);
    gemm256_kernel<<<g, 512, 0, stream>>>(xb, Wt, out, M, N, K);
}